// Round 1
// baseline (945.292 us; speedup 1.0000x reference)
//
#include <hip/hip_runtime.h>
#include <hip/hip_bf16.h>

#define BSZ 4
#define NN  256
#define DXX 256
#define DEE 64
#define DYY 64

// ---- workspace layout (float offsets) ----
#define OFF_Q     0          // 262144
#define OFF_K     262144     // 262144
#define OFF_V     524288     // 262144
#define OFF_XW    786432     // 262144
#define OFF_YE1   1048576    // 1024
#define OFF_YE2   1049600    // 1024
#define OFF_YX1   1050624    // 1024
#define OFF_YX2   1051648    // 1024
#define OFF_PX    1052672    // 4096  (pool(x): mean|min|max|std per b, 4*1024)
#define OFF_PE    1056768    // 1024  (pool(e): 4*256)
#define OFF_EPART 1057792    // 4*64*64*4 = 65536 partials
// total ~ 1123328 floats = 4.3 MB

__device__ __forceinline__ float bflo(unsigned u) { return __uint_as_float(u << 16); }
__device__ __forceinline__ float bfhi(unsigned u) { return __uint_as_float(u & 0xffff0000u); }

// out[m,c] = (sum_d in[m,d] * W[d,c] + bias[c]) * nm[m]   (M=1024, K=256, Ncols=256)
__global__ void rowgemm_kernel(const float* __restrict__ in, const float* __restrict__ W,
                               const float* __restrict__ bias, const float* __restrict__ nm,
                               float* __restrict__ out) {
    const int t  = threadIdx.x;
    const int m0 = blockIdx.x * 16;
    __shared__ float xl[16][256];
    for (int r = 0; r < 16; ++r) xl[r][t] = in[(m0 + r) * 256 + t];
    __syncthreads();
    float acc[16];
#pragma unroll
    for (int r = 0; r < 16; ++r) acc[r] = 0.f;
    for (int d = 0; d < 256; d += 4) {
        float w0 = W[(d + 0) * 256 + t];
        float w1 = W[(d + 1) * 256 + t];
        float w2 = W[(d + 2) * 256 + t];
        float w3 = W[(d + 3) * 256 + t];
#pragma unroll
        for (int r = 0; r < 16; ++r) {
            float4 ev = *(const float4*)&xl[r][d];
            acc[r] = fmaf(ev.x, w0, fmaf(ev.y, w1, fmaf(ev.z, w2, fmaf(ev.w, w3, acc[r]))));
        }
    }
    const float bv = bias ? bias[t] : 0.f;
#pragma unroll
    for (int r = 0; r < 16; ++r) {
        int m = m0 + r;
        float mv = nm ? nm[m] : 1.f;
        out[m * 256 + t] = (acc[r] + bv) * mv;
    }
}

// y projections: ye1,ye2,yx1,yx2  (4 x 256 each)
__global__ void yproj_kernel(const float* __restrict__ y,
                             const float* __restrict__ Wye_add, const float* __restrict__ Wye_mul,
                             const float* __restrict__ Wyx_add, const float* __restrict__ Wyx_mul,
                             float* __restrict__ ws) {
    const int c = threadIdx.x;
    for (int b = 0; b < BSZ; ++b) {
        float a1 = 0.f, a2 = 0.f, a3 = 0.f, a4 = 0.f;
        for (int k = 0; k < DYY; ++k) {
            float yv = y[b * DYY + k];
            a1 = fmaf(yv, Wye_add[k * 256 + c], a1);
            a2 = fmaf(yv, Wye_mul[k * 256 + c], a2);
            a3 = fmaf(yv, Wyx_add[k * 256 + c], a3);
            a4 = fmaf(yv, Wyx_mul[k * 256 + c], a4);
        }
        ws[OFF_YE1 + b * 256 + c] = a1;
        ws[OFF_YE2 + b * 256 + c] = a2;
        ws[OFF_YX1 + b * 256 + c] = a3;
        ws[OFF_YX2 + b * 256 + c] = a4;
    }
}

// stage A of e-pool: per (b, slab of 1024 rows) partial sum/sumsq/min/max per d
__global__ void epoolA_kernel(const float* __restrict__ e, float* __restrict__ ws) {
    const int s = blockIdx.x;   // 0..63
    const int b = blockIdx.y;   // 0..3
    const int t = threadIdx.x;
    const int d = t & 63, g = t >> 6;
    const float* base = e + ((size_t)b * 65536 + s * 1024) * 64;
    float sum = 0.f, sq = 0.f, mn = 1e30f, mx = -1e30f;
    for (int rr = 0; rr < 256; ++rr) {
        float v = base[(rr * 4 + g) * 64 + d];
        sum += v; sq = fmaf(v, v, sq);
        mn = fminf(mn, v); mx = fmaxf(mx, v);
    }
    __shared__ float red[4][4][64];
    red[0][g][d] = sum; red[1][g][d] = sq; red[2][g][d] = mn; red[3][g][d] = mx;
    __syncthreads();
    if (g == 0) {
        float S = 0.f, Q = 0.f, Mn = 1e30f, Mx = -1e30f;
#pragma unroll
        for (int gg = 0; gg < 4; ++gg) {
            S += red[0][gg][d]; Q += red[1][gg][d];
            Mn = fminf(Mn, red[2][gg][d]); Mx = fmaxf(Mx, red[3][gg][d]);
        }
        float* ep = ws + OFF_EPART + ((b * 64 + s) * 64 + d) * 4;
        ep[0] = S; ep[1] = Q; ep[2] = Mn; ep[3] = Mx;
    }
}

// stage B: x-pool (per b,c over 256 rows) + e-pool combine
__global__ void poolB_kernel(const float* __restrict__ x, float* __restrict__ ws) {
    const int b = blockIdx.x;
    const int t = threadIdx.x;
    float s = 0.f, q = 0.f, mn = 1e30f, mx = -1e30f;
    for (int i = 0; i < 256; ++i) {
        float v = x[(b * 256 + i) * 256 + t];
        s += v; q = fmaf(v, v, q);
        mn = fminf(mn, v); mx = fmaxf(mx, v);
    }
    float mean = s * (1.f / 256.f);
    float var  = (q - s * s * (1.f / 256.f)) * (1.f / 255.f);
    var = fmaxf(var, 0.f);
    ws[OFF_PX + b * 1024 + t]       = mean;
    ws[OFF_PX + b * 1024 + 256 + t] = mn;
    ws[OFF_PX + b * 1024 + 512 + t] = mx;
    ws[OFF_PX + b * 1024 + 768 + t] = sqrtf(var);
    if (t < 64) {
        float S = 0.f, Q = 0.f, Mn = 1e30f, Mx = -1e30f;
        for (int ss = 0; ss < 64; ++ss) {
            const float* ep = ws + OFF_EPART + ((b * 64 + ss) * 64 + t) * 4;
            float4 p = *(const float4*)ep;
            S += p.x; Q += p.y; Mn = fminf(Mn, p.z); Mx = fmaxf(Mx, p.w);
        }
        const float n = 65536.f;
        float meane = S / n;
        float vare  = (Q - S * S / n) / (n - 1.f);
        vare = fmaxf(vare, 0.f);
        ws[OFF_PE + b * 256 + t]       = meane;
        ws[OFF_PE + b * 256 + 64 + t]  = Mn;
        ws[OFF_PE + b * 256 + 128 + t] = Mx;
        ws[OFF_PE + b * 256 + 192 + t] = sqrtf(vare);
    }
}

// newY = (y@Wyy + pool(e)@Wey+bey + pool(x)@Wxy+bxy) @ Wy_out + by_out
__global__ void newy_kernel(const float* __restrict__ y,
                            const float* __restrict__ Wyy, const float* __restrict__ Wxy,
                            const float* __restrict__ bxy, const float* __restrict__ Wey,
                            const float* __restrict__ bey, const float* __restrict__ Wy_out,
                            const float* __restrict__ by_out,
                            const float* __restrict__ ws, float* __restrict__ outY) {
    const int t = threadIdx.x;
    const int b = t >> 6, o = t & 63;
    __shared__ float sy[4][64];
    float a = bxy[o] + bey[o];
    for (int k = 0; k < 64; ++k)   a = fmaf(y[b * 64 + k],        Wyy[k * 64 + o], a);
    for (int k = 0; k < 256; ++k)  a = fmaf(ws[OFF_PE + b * 256 + k], Wey[k * 64 + o], a);
    for (int k = 0; k < 1024; ++k) a = fmaf(ws[OFF_PX + b * 1024 + k], Wxy[k * 64 + o], a);
    sy[b][o] = a;
    __syncthreads();
    float r = by_out[o];
    for (int k = 0; k < 64; ++k) r = fmaf(sy[b][k], Wy_out[k * 64 + o], r);
    outY[b * 64 + o] = r;
}

// ---- the big fused kernel: per (b,i): E1/E2, Y, online softmax per channel,
// Yp @ We_out -> newE, weighted -> xw ----
__global__ __launch_bounds__(256) void fused_kernel(
    const float* __restrict__ e, const float* __restrict__ nmask,
    const float* __restrict__ Wm, const float* __restrict__ Wa,
    const float* __restrict__ We_out, const float* __restrict__ be_out,
    const float* __restrict__ ws, float* __restrict__ outE, float* __restrict__ xw) {

    const int i = blockIdx.x, b = blockIdx.y;
    const int c = threadIdx.x;

    __shared__ __align__(16) float eeb[32 * 64];               // 8 KB
    __shared__ __align__(16) __hip_bfloat16 ypl[32 * 256];     // 16 KB
    __shared__ __align__(16) __hip_bfloat16 weo[256 * 64];     // 32 KB
    __shared__ float nml[256];                                 // 1 KB

    // stage We_out (bf16) and node mask
    for (int kk = 0; kk < 64; ++kk) {
        int idx = kk * 256 + c;
        weo[idx] = __float2bfloat16(We_out[idx]);
    }
    nml[c] = nmask[b * 256 + c];
    __syncthreads();

    const float mi   = nml[i];
    const float qc   = ws[OFF_Q + (b * 256 + i) * 256 + c];
    const float ye1c = ws[OFF_YE1 + b * 256 + c];
    const float ye2c = ws[OFF_YE2 + b * 256 + c] + 1.f;
    const float rs   = 0.17677669529663687f; // 1/sqrt(32)
    const float* kbuf = ws + OFF_K + (size_t)b * 65536;
    const float* vbuf = ws + OFF_V + (size_t)b * 65536;

    float mrun = -1e30f, lrun = 0.f, wrun = 0.f;

    const int ddo = (c & 31) * 2;   // newE output dd pair
    const int jg  = c >> 5;         // newE output j group

    for (int chunk = 0; chunk < 8; ++chunk) {
        const int j0 = chunk * 32;
        __syncthreads();  // previous chunk's GEMM done before overwriting LDS
        // load e[b,i,j0..j0+31,:] -> eeb
        {
            const float* ebase = e + (((size_t)(b * 256 + i)) * 256 + j0) * 64;
            for (int kk = 0; kk < 8; ++kk) eeb[kk * 256 + c] = ebase[kk * 256 + c];
        }
        __syncthreads();

        // E1/E2 for this thread's channel across 32 j's
        float acc1[32], acc2[32];
#pragma unroll
        for (int jj = 0; jj < 32; ++jj) { acc1[jj] = 0.f; acc2[jj] = 0.f; }
        for (int d = 0; d < 64; d += 4) {
            float wm0 = Wm[(d + 0) * 256 + c], wm1 = Wm[(d + 1) * 256 + c];
            float wm2 = Wm[(d + 2) * 256 + c], wm3 = Wm[(d + 3) * 256 + c];
            float wa0 = Wa[(d + 0) * 256 + c], wa1 = Wa[(d + 1) * 256 + c];
            float wa2 = Wa[(d + 2) * 256 + c], wa3 = Wa[(d + 3) * 256 + c];
#pragma unroll
            for (int jj = 0; jj < 32; ++jj) {
                float4 ev = *(const float4*)&eeb[jj * 64 + d];
                acc1[jj] = fmaf(ev.x, wm0, fmaf(ev.y, wm1, fmaf(ev.z, wm2, fmaf(ev.w, wm3, acc1[jj]))));
                acc2[jj] = fmaf(ev.x, wa0, fmaf(ev.y, wa1, fmaf(ev.z, wa2, fmaf(ev.w, wa3, acc2[jj]))));
            }
        }

        // Y, Yp -> LDS(bf16), online softmax
#pragma unroll 4
        for (int jj = 0; jj < 32; ++jj) {
            const int j = j0 + jj;
            float kj  = kbuf[j * 256 + c];
            float vj  = vbuf[j * 256 + c];
            float mj  = nml[j];
            float emv = mi * mj;
            float qk  = qc * kj * rs;
            float Yv  = fmaf(qk, fmaf(acc1[jj], emv, 1.f), acc2[jj] * emv);
            ypl[jj * 256 + c] = __float2bfloat16(fmaf(ye2c, Yv, ye1c));
            float yeff = (mj > 0.f) ? Yv : -1e9f;
            float mnew = fmaxf(mrun, yeff);
            float al = __expf(mrun - mnew);
            float p  = __expf(yeff - mnew);
            lrun = fmaf(lrun, al, p);
            wrun = fmaf(wrun, al, p * vj);
            mrun = mnew;
        }
        __syncthreads();

        // newE chunk GEMM: out[jl, dd] = sum_c Yp[jl,c]*We_out[c,dd]
        float accE[4][2];
#pragma unroll
        for (int kk = 0; kk < 4; ++kk) { accE[kk][0] = 0.f; accE[kk][1] = 0.f; }
        for (int cc = 0; cc < 256; cc += 8) {
            float wl[8], wh[8];
#pragma unroll
            for (int u = 0; u < 8; ++u) {
                unsigned wp = *(const unsigned*)&weo[(cc + u) * 64 + ddo];
                wl[u] = bflo(wp); wh[u] = bfhi(wp);
            }
#pragma unroll
            for (int kk = 0; kk < 4; ++kk) {
                const int jl = jg + kk * 8;
                uint4 yr = *(const uint4*)&ypl[jl * 256 + cc];
                float y0 = bflo(yr.x), y1 = bfhi(yr.x);
                float y2 = bflo(yr.y), y3 = bfhi(yr.y);
                float y4 = bflo(yr.z), y5 = bfhi(yr.z);
                float y6 = bflo(yr.w), y7 = bfhi(yr.w);
                accE[kk][0] = fmaf(y0, wl[0], fmaf(y1, wl[1], fmaf(y2, wl[2], fmaf(y3, wl[3],
                              fmaf(y4, wl[4], fmaf(y5, wl[5], fmaf(y6, wl[6], fmaf(y7, wl[7], accE[kk][0]))))))));
                accE[kk][1] = fmaf(y0, wh[0], fmaf(y1, wh[1], fmaf(y2, wh[2], fmaf(y3, wh[3],
                              fmaf(y4, wh[4], fmaf(y5, wh[5], fmaf(y6, wh[6], fmaf(y7, wh[7], accE[kk][1]))))))));
            }
        }
        const float b0 = be_out[ddo], b1 = be_out[ddo + 1];
#pragma unroll
        for (int kk = 0; kk < 4; ++kk) {
            const int j = j0 + jg + kk * 8;
            float emv = mi * nml[j];
            float2 st;
            st.x = (accE[kk][0] + b0) * emv;
            st.y = (accE[kk][1] + b1) * emv;
            *(float2*)&outE[(((size_t)(b * 256 + i)) * 256 + j) * 64 + ddo] = st;
        }
    }

    // weighted + yx transform -> xw
    float weighted = wrun / lrun;
    float yx1c = ws[OFF_YX1 + b * 256 + c];
    float yx2c = ws[OFF_YX2 + b * 256 + c] + 1.f;
    xw[(b * 256 + i) * 256 + c] = fmaf(yx2c, weighted, yx1c);
}

extern "C" void kernel_launch(void* const* d_in, const int* in_sizes, int n_in,
                              void* d_out, int out_size, void* d_ws, size_t ws_size,
                              hipStream_t stream) {
    const float* x        = (const float*)d_in[0];
    const float* e        = (const float*)d_in[1];
    const float* y        = (const float*)d_in[2];
    const float* nm       = (const float*)d_in[3];
    const float* Wq       = (const float*)d_in[4];
    const float* Wk       = (const float*)d_in[5];
    const float* Wv       = (const float*)d_in[6];
    const float* We_mul   = (const float*)d_in[7];
    const float* We_add   = (const float*)d_in[8];
    const float* Wye_add  = (const float*)d_in[9];
    const float* Wye_mul  = (const float*)d_in[10];
    const float* Wyx_add  = (const float*)d_in[11];
    const float* Wyx_mul  = (const float*)d_in[12];
    const float* Wyy      = (const float*)d_in[13];
    const float* Wxy      = (const float*)d_in[14];
    const float* bxy      = (const float*)d_in[15];
    const float* Wey      = (const float*)d_in[16];
    const float* bey      = (const float*)d_in[17];
    const float* We_out   = (const float*)d_in[18];
    const float* be_out   = (const float*)d_in[19];
    const float* Wx_out   = (const float*)d_in[20];
    const float* bx_out   = (const float*)d_in[21];
    const float* Wy_out   = (const float*)d_in[22];
    const float* by_out   = (const float*)d_in[23];

    float* ws   = (float*)d_ws;
    float* outX = (float*)d_out;                       // 262144
    float* outE = (float*)d_out + 262144;              // 16777216
    float* outY = (float*)d_out + 262144 + 16777216;   // 256

    // q, k, v projections (masked)
    rowgemm_kernel<<<64, 256, 0, stream>>>(x, Wq, nullptr, nm, ws + OFF_Q);
    rowgemm_kernel<<<64, 256, 0, stream>>>(x, Wk, nullptr, nm, ws + OFF_K);
    rowgemm_kernel<<<64, 256, 0, stream>>>(x, Wv, nullptr, nm, ws + OFF_V);
    // y projections
    yproj_kernel<<<1, 256, 0, stream>>>(y, Wye_add, Wye_mul, Wyx_add, Wyx_mul, ws);
    // pooling for newY
    epoolA_kernel<<<dim3(64, 4), 256, 0, stream>>>(e, ws);
    poolB_kernel<<<4, 256, 0, stream>>>(x, ws);
    newy_kernel<<<1, 256, 0, stream>>>(y, Wyy, Wxy, bxy, Wey, bey, Wy_out, by_out, ws, outY);
    // fused E1/E2 + Y + softmax + newE + weighted
    fused_kernel<<<dim3(256, 4), 256, 0, stream>>>(e, nm, We_mul, We_add, We_out, be_out,
                                                   ws, outE, ws + OFF_XW);
    // newX = xw @ Wx_out + bx_out, masked
    rowgemm_kernel<<<64, 256, 0, stream>>>(ws + OFF_XW, Wx_out, bx_out, nm, outX);
}

// Round 2
// 440.966 us; speedup vs baseline: 2.1437x; 2.1437x over previous
//
#include <hip/hip_runtime.h>
#include <hip/hip_bf16.h>

#define BSZ 4
#define NN  256
#define DXX 256
#define DEE 64
#define DYY 64

// ---- workspace layout (float offsets) ----
#define OFF_Q     0          // 262144
#define OFF_K     262144     // 262144
#define OFF_V     524288     // 262144
#define OFF_XW    786432     // 262144
#define OFF_YE1   1048576    // 1024
#define OFF_YE2   1049600    // 1024
#define OFF_YX1   1050624    // 1024
#define OFF_YX2   1051648    // 1024
#define OFF_PX    1052672    // 4096
#define OFF_PE    1056768    // 1024
#define OFF_EPART 1057792    // 65536
// total ~1123328 floats = 4.5 MB

typedef __attribute__((ext_vector_type(8))) short bf16x8;
typedef __attribute__((ext_vector_type(4))) float f32x4;

__device__ __forceinline__ short f2bf(float f) {
    unsigned u = __float_as_uint(f);
    unsigned r = u + 0x7fffu + ((u >> 16) & 1u);
    return (short)(r >> 16);
}

// out[m,c] = (sum_d in[m,d] * W[d,c] + bias[c]) * nm[m]
__global__ void rowgemm_kernel(const float* __restrict__ in, const float* __restrict__ W,
                               const float* __restrict__ bias, const float* __restrict__ nm,
                               float* __restrict__ out) {
    const int t  = threadIdx.x;
    const int m0 = blockIdx.x * 16;
    __shared__ float xl[16][256];
    for (int r = 0; r < 16; ++r) xl[r][t] = in[(m0 + r) * 256 + t];
    __syncthreads();
    float acc[16];
#pragma unroll
    for (int r = 0; r < 16; ++r) acc[r] = 0.f;
    for (int d = 0; d < 256; d += 4) {
        float w0 = W[(d + 0) * 256 + t];
        float w1 = W[(d + 1) * 256 + t];
        float w2 = W[(d + 2) * 256 + t];
        float w3 = W[(d + 3) * 256 + t];
#pragma unroll
        for (int r = 0; r < 16; ++r) {
            float4 ev = *(const float4*)&xl[r][d];
            acc[r] = fmaf(ev.x, w0, fmaf(ev.y, w1, fmaf(ev.z, w2, fmaf(ev.w, w3, acc[r]))));
        }
    }
    const float bv = bias ? bias[t] : 0.f;
#pragma unroll
    for (int r = 0; r < 16; ++r) {
        int m = m0 + r;
        float mv = nm ? nm[m] : 1.f;
        out[m * 256 + t] = (acc[r] + bv) * mv;
    }
}

// q,k,v in one launch: blockIdx.y selects projection
__global__ void qkv_kernel(const float* __restrict__ x, const float* __restrict__ Wq,
                           const float* __restrict__ Wk, const float* __restrict__ Wv,
                           const float* __restrict__ nm, float* __restrict__ ws) {
    const int t  = threadIdx.x;
    const int m0 = blockIdx.x * 16;
    const int which = blockIdx.y;
    const float* W = which == 0 ? Wq : (which == 1 ? Wk : Wv);
    float* out = ws + (size_t)which * 262144;  // OFF_Q / OFF_K / OFF_V
    __shared__ float xl[16][256];
    for (int r = 0; r < 16; ++r) xl[r][t] = x[(m0 + r) * 256 + t];
    __syncthreads();
    float acc[16];
#pragma unroll
    for (int r = 0; r < 16; ++r) acc[r] = 0.f;
    for (int d = 0; d < 256; d += 4) {
        float w0 = W[(d + 0) * 256 + t];
        float w1 = W[(d + 1) * 256 + t];
        float w2 = W[(d + 2) * 256 + t];
        float w3 = W[(d + 3) * 256 + t];
#pragma unroll
        for (int r = 0; r < 16; ++r) {
            float4 ev = *(const float4*)&xl[r][d];
            acc[r] = fmaf(ev.x, w0, fmaf(ev.y, w1, fmaf(ev.z, w2, fmaf(ev.w, w3, acc[r]))));
        }
    }
#pragma unroll
    for (int r = 0; r < 16; ++r) {
        int m = m0 + r;
        out[m * 256 + t] = acc[r] * nm[m];
    }
}

// y projections, one block per b
__global__ void yproj_kernel(const float* __restrict__ y,
                             const float* __restrict__ Wye_add, const float* __restrict__ Wye_mul,
                             const float* __restrict__ Wyx_add, const float* __restrict__ Wyx_mul,
                             float* __restrict__ ws) {
    const int c = threadIdx.x;
    const int b = blockIdx.x;
    float a1 = 0.f, a2 = 0.f, a3 = 0.f, a4 = 0.f;
    for (int k = 0; k < DYY; ++k) {
        float yv = y[b * DYY + k];
        a1 = fmaf(yv, Wye_add[k * 256 + c], a1);
        a2 = fmaf(yv, Wye_mul[k * 256 + c], a2);
        a3 = fmaf(yv, Wyx_add[k * 256 + c], a3);
        a4 = fmaf(yv, Wyx_mul[k * 256 + c], a4);
    }
    ws[OFF_YE1 + b * 256 + c] = a1;
    ws[OFF_YE2 + b * 256 + c] = a2;
    ws[OFF_YX1 + b * 256 + c] = a3;
    ws[OFF_YX2 + b * 256 + c] = a4;
}

__global__ void epoolA_kernel(const float* __restrict__ e, float* __restrict__ ws) {
    const int s = blockIdx.x;
    const int b = blockIdx.y;
    const int t = threadIdx.x;
    const int d = t & 63, g = t >> 6;
    const float* base = e + ((size_t)b * 65536 + s * 1024) * 64;
    float sum = 0.f, sq = 0.f, mn = 1e30f, mx = -1e30f;
    for (int rr = 0; rr < 256; ++rr) {
        float v = base[(rr * 4 + g) * 64 + d];
        sum += v; sq = fmaf(v, v, sq);
        mn = fminf(mn, v); mx = fmaxf(mx, v);
    }
    __shared__ float red[4][4][64];
    red[0][g][d] = sum; red[1][g][d] = sq; red[2][g][d] = mn; red[3][g][d] = mx;
    __syncthreads();
    if (g == 0) {
        float S = 0.f, Q = 0.f, Mn = 1e30f, Mx = -1e30f;
#pragma unroll
        for (int gg = 0; gg < 4; ++gg) {
            S += red[0][gg][d]; Q += red[1][gg][d];
            Mn = fminf(Mn, red[2][gg][d]); Mx = fmaxf(Mx, red[3][gg][d]);
        }
        float* ep = ws + OFF_EPART + ((b * 64 + s) * 64 + d) * 4;
        ep[0] = S; ep[1] = Q; ep[2] = Mn; ep[3] = Mx;
    }
}

__global__ void poolB_kernel(const float* __restrict__ x, float* __restrict__ ws) {
    const int b = blockIdx.x;
    const int t = threadIdx.x;
    float s = 0.f, q = 0.f, mn = 1e30f, mx = -1e30f;
    for (int i = 0; i < 256; ++i) {
        float v = x[(b * 256 + i) * 256 + t];
        s += v; q = fmaf(v, v, q);
        mn = fminf(mn, v); mx = fmaxf(mx, v);
    }
    float mean = s * (1.f / 256.f);
    float var  = (q - s * s * (1.f / 256.f)) * (1.f / 255.f);
    var = fmaxf(var, 0.f);
    ws[OFF_PX + b * 1024 + t]       = mean;
    ws[OFF_PX + b * 1024 + 256 + t] = mn;
    ws[OFF_PX + b * 1024 + 512 + t] = mx;
    ws[OFF_PX + b * 1024 + 768 + t] = sqrtf(var);
    if (t < 64) {
        float S = 0.f, Q = 0.f, Mn = 1e30f, Mx = -1e30f;
        for (int ss = 0; ss < 64; ++ss) {
            const float* ep = ws + OFF_EPART + ((b * 64 + ss) * 64 + t) * 4;
            float4 p = *(const float4*)ep;
            S += p.x; Q += p.y; Mn = fminf(Mn, p.z); Mx = fmaxf(Mx, p.w);
        }
        const float n = 65536.f;
        float meane = S / n;
        float vare  = (Q - S * S / n) / (n - 1.f);
        vare = fmaxf(vare, 0.f);
        ws[OFF_PE + b * 256 + t]       = meane;
        ws[OFF_PE + b * 256 + 64 + t]  = Mn;
        ws[OFF_PE + b * 256 + 128 + t] = Mx;
        ws[OFF_PE + b * 256 + 192 + t] = sqrtf(vare);
    }
}

__global__ void newy_kernel(const float* __restrict__ y,
                            const float* __restrict__ Wyy, const float* __restrict__ Wxy,
                            const float* __restrict__ bxy, const float* __restrict__ Wey,
                            const float* __restrict__ bey, const float* __restrict__ Wy_out,
                            const float* __restrict__ by_out,
                            const float* __restrict__ ws, float* __restrict__ outY) {
    const int t = threadIdx.x;
    const int b = t >> 6, o = t & 63;
    __shared__ float sy[4][64];
    float a = bxy[o] + bey[o];
    for (int k = 0; k < 64; ++k)   a = fmaf(y[b * 64 + k],            Wyy[k * 64 + o], a);
    for (int k = 0; k < 256; ++k)  a = fmaf(ws[OFF_PE + b * 256 + k], Wey[k * 64 + o], a);
    for (int k = 0; k < 1024; ++k) a = fmaf(ws[OFF_PX + b * 1024 + k], Wxy[k * 64 + o], a);
    sy[b][o] = a;
    __syncthreads();
    float r = by_out[o];
    for (int k = 0; k < 64; ++k) r = fmaf(sy[b][k], Wy_out[k * 64 + o], r);
    outY[b * 64 + o] = r;
}

// ---- fused MFMA kernel: per (b,i): E1/E2 (MFMA), Y epilogue + online softmax,
// Yp (bf16, LDS) @ We_out (MFMA) -> newE, weighted -> xw ----
#define EBP  72    // e-chunk LDS row pitch (bf16 units); 144 B = 9*16 -> aligned b128, 2-way banks
#define YPLP 264   // ypl row pitch (bf16 units); 528 B = 33*16 -> aligned b128, 2-way banks

__global__ __launch_bounds__(256, 2) void fusedmfma_kernel(
    const float* __restrict__ e, const float* __restrict__ nmask,
    const float* __restrict__ Wm, const float* __restrict__ Wa,
    const float* __restrict__ We_out, const float* __restrict__ be_out,
    const float* __restrict__ ws, float* __restrict__ outE, float* __restrict__ xw) {

    const int i = blockIdx.x, b = blockIdx.y;
    const int tid  = threadIdx.x;
    const int w    = tid >> 6;
    const int lane = tid & 63;
    const int quad = lane >> 4, l16 = lane & 15;

    __shared__ __align__(16) short ebuf[2][32 * EBP];   // 9.2 KB
    __shared__ __align__(16) short ypl[32 * YPLP];      // 16.9 KB
    __shared__ float nml[256];

    nml[tid] = nmask[b * 256 + tid];

    // ---- persistent B-frags in registers ----
    // E1/E2: wave w covers columns cw..cw+63 (4 c-tiles); B[k=s*32+quad*8+jj][n=c]
    bf16x8 bm[4][2], ba[4][2], bw[8];
    const int cw = w * 64;
#pragma unroll
    for (int ct = 0; ct < 4; ++ct) {
        const int c = cw + ct * 16 + l16;
#pragma unroll
        for (int s = 0; s < 2; ++s) {
            bf16x8 t1, t2;
#pragma unroll
            for (int jj = 0; jj < 8; ++jj) {
                const int d = s * 32 + quad * 8 + jj;
                t1[jj] = f2bf(Wm[d * 256 + c]);
                t2[jj] = f2bf(Wa[d * 256 + c]);
            }
            bm[ct][s] = t1; ba[ct][s] = t2;
        }
    }
    const int cp = w * 16 + l16;   // newE output column for this lane
    {
#pragma unroll
        for (int s = 0; s < 8; ++s) {
            bf16x8 t;
#pragma unroll
            for (int jj = 0; jj < 8; ++jj) {
                const int cch = s * 32 + quad * 8 + jj;
                t[jj] = f2bf(We_out[cch * 64 + cp]);
            }
            bw[s] = t;
        }
    }
    const float bo = be_out[cp];

    // per-lane per-c-tile scalars
    const float rs = 0.17677669529663687f; // 1/sqrt(32)
    float qc[4], ye1c[4], ye2c[4];
#pragma unroll
    for (int ct = 0; ct < 4; ++ct) {
        const int c = cw + ct * 16 + l16;
        qc[ct]   = ws[OFF_Q + (size_t)(b * 256 + i) * 256 + c] * rs;
        ye1c[ct] = ws[OFF_YE1 + b * 256 + c];
        ye2c[ct] = ws[OFF_YE2 + b * 256 + c] + 1.f;
    }
    const float* kb = ws + OFF_K + (size_t)b * 65536;
    const float* vb = ws + OFF_V + (size_t)b * 65536;

    // stage e chunk 0 (rows 0..31) into ebuf[0]
    const float* eb = e + ((size_t)(b * 256 + i)) * 256 * 64;
    {
        const int jr = tid >> 3, c0 = (tid & 7) * 8;
        float4 A = *(const float4*)(eb + jr * 64 + c0);
        float4 B = *(const float4*)(eb + jr * 64 + c0 + 4);
        short* dst = &ebuf[0][jr * EBP + c0];
        dst[0] = f2bf(A.x); dst[1] = f2bf(A.y); dst[2] = f2bf(A.z); dst[3] = f2bf(A.w);
        dst[4] = f2bf(B.x); dst[5] = f2bf(B.y); dst[6] = f2bf(B.z); dst[7] = f2bf(B.w);
    }
    __syncthreads();
    const float mi = nml[i];

    float msm[4], lsm[4], wsm[4];
#pragma unroll
    for (int ct = 0; ct < 4; ++ct) { msm[ct] = -1e30f; lsm[ct] = 0.f; wsm[ct] = 0.f; }

    for (int chunk = 0; chunk < 8; ++chunk) {
        const int cur = chunk & 1, j0 = chunk * 32;

        // A-frags for E1/E2 from current e-chunk (shared across waves)
        bf16x8 ae[2][2];
#pragma unroll
        for (int jt = 0; jt < 2; ++jt)
#pragma unroll
            for (int s = 0; s < 2; ++s)
                ae[jt][s] = *(const bf16x8*)&ebuf[cur][(jt * 16 + l16) * EBP + s * 32 + quad * 8];

        // prefetch next e chunk (global)
        float4 pfA, pfB;
        const int jrn = tid >> 3, c0n = (tid & 7) * 8;
        if (chunk < 7) {
            const float* nb = eb + (size_t)(j0 + 32 + jrn) * 64 + c0n;
            pfA = *(const float4*)(nb);
            pfB = *(const float4*)(nb + 4);
        }

        // mask values for this chunk's rows owned by this lane
        float mjv[8], emv[8];
#pragma unroll
        for (int jt = 0; jt < 2; ++jt)
#pragma unroll
            for (int r = 0; r < 4; ++r) {
                const float mj = nml[j0 + jt * 16 + quad * 4 + r];
                mjv[jt * 4 + r] = mj;
                emv[jt * 4 + r] = mi * mj;
            }

#pragma unroll
        for (int ct = 0; ct < 4; ++ct) {
            f32x4 a1_0 = {0.f, 0.f, 0.f, 0.f}, a1_1 = {0.f, 0.f, 0.f, 0.f};
            f32x4 a2_0 = {0.f, 0.f, 0.f, 0.f}, a2_1 = {0.f, 0.f, 0.f, 0.f};
#pragma unroll
            for (int s = 0; s < 2; ++s) {
                a1_0 = __builtin_amdgcn_mfma_f32_16x16x32_bf16(ae[0][s], bm[ct][s], a1_0, 0, 0, 0);
                a1_1 = __builtin_amdgcn_mfma_f32_16x16x32_bf16(ae[1][s], bm[ct][s], a1_1, 0, 0, 0);
                a2_0 = __builtin_amdgcn_mfma_f32_16x16x32_bf16(ae[0][s], ba[ct][s], a2_0, 0, 0, 0);
                a2_1 = __builtin_amdgcn_mfma_f32_16x16x32_bf16(ae[1][s], ba[ct][s], a2_1, 0, 0, 0);
            }
            const int c = cw + ct * 16 + l16;
            float Ys[8], Vs[8];
#pragma unroll
            for (int jt = 0; jt < 2; ++jt) {
#pragma unroll
                for (int r = 0; r < 4; ++r) {
                    const int u  = jt * 4 + r;
                    const int jl = jt * 16 + quad * 4 + r;
                    const int jg = j0 + jl;
                    const float kj = kb[jg * 256 + c];
                    const float vj = vb[jg * 256 + c];
                    const float e1v = (jt == 0) ? a1_0[r] : a1_1[r];
                    const float e2v = (jt == 0) ? a2_0[r] : a2_1[r];
                    const float em = emv[u];
                    const float Yv = fmaf(qc[ct] * kj, fmaf(e1v, em, 1.f), e2v * em);
                    ypl[jl * YPLP + c] = f2bf(fmaf(ye2c[ct], Yv, ye1c[ct]));
                    Ys[u] = (mjv[u] > 0.f) ? Yv : -1e9f;
                    Vs[u] = vj;
                }
            }
            // batched online softmax update for this lane's column
            float cm = Ys[0];
#pragma unroll
            for (int u = 1; u < 8; ++u) cm = fmaxf(cm, Ys[u]);
            const float mnew = fmaxf(msm[ct], cm);
            const float al = __expf(msm[ct] - mnew);
            float sum = 0.f, wsum = 0.f;
#pragma unroll
            for (int u = 0; u < 8; ++u) {
                const float p = __expf(Ys[u] - mnew);
                sum += p; wsum = fmaf(p, Vs[u], wsum);
            }
            lsm[ct] = fmaf(lsm[ct], al, sum);
            wsm[ct] = fmaf(wsm[ct], al, wsum);
            msm[ct] = mnew;
        }

        // stage next e chunk to the other buffer
        if (chunk < 7) {
            short* dst = &ebuf[cur ^ 1][jrn * EBP + c0n];
            dst[0] = f2bf(pfA.x); dst[1] = f2bf(pfA.y); dst[2] = f2bf(pfA.z); dst[3] = f2bf(pfA.w);
            dst[4] = f2bf(pfB.x); dst[5] = f2bf(pfB.y); dst[6] = f2bf(pfB.z); dst[7] = f2bf(pfB.w);
        }
        __syncthreads();   // ypl complete

        // newE chunk GEMM: D[j, cp] = sum_c Yp[j,c] * We_out[c,cp]
        f32x4 acc0 = {0.f, 0.f, 0.f, 0.f}, acc1 = {0.f, 0.f, 0.f, 0.f};
#pragma unroll
        for (int s = 0; s < 8; ++s) {
            bf16x8 a0 = *(const bf16x8*)&ypl[(l16) * YPLP + s * 32 + quad * 8];
            bf16x8 a1 = *(const bf16x8*)&ypl[(16 + l16) * YPLP + s * 32 + quad * 8];
            acc0 = __builtin_amdgcn_mfma_f32_16x16x32_bf16(a0, bw[s], acc0, 0, 0, 0);
            acc1 = __builtin_amdgcn_mfma_f32_16x16x32_bf16(a1, bw[s], acc1, 0, 0, 0);
        }
#pragma unroll
        for (int jt = 0; jt < 2; ++jt)
#pragma unroll
            for (int r = 0; r < 4; ++r) {
                const int jg = j0 + jt * 16 + quad * 4 + r;
                const float em2 = mi * nml[jg];
                const float av = (jt == 0) ? acc0[r] : acc1[r];
                outE[((size_t)(b * 256 + i) * 256 + jg) * 64 + cp] = (av + bo) * em2;
            }
        __syncthreads();   // ypl consumed; ebuf[nxt] staged & visible
    }

    // cross-quad softmax combine + xw store
#pragma unroll
    for (int ct = 0; ct < 4; ++ct) {
        float m = msm[ct], l = lsm[ct], wv = wsm[ct];
#pragma unroll
        for (int off = 16; off < 64; off <<= 1) {
            const float m2 = __shfl_xor(m, off, 64);
            const float l2 = __shfl_xor(l, off, 64);
            const float w2 = __shfl_xor(wv, off, 64);
            const float mn = fmaxf(m, m2);
            const float s1 = __expf(m - mn), s2 = __expf(m2 - mn);
            l = l * s1 + l2 * s2;
            wv = wv * s1 + w2 * s2;
            m = mn;
        }
        if (quad == 0) {
            const int c = cw + ct * 16 + l16;
            const float weighted = wv / l;
            const float yx1 = ws[OFF_YX1 + b * 256 + c];
            const float yx2 = ws[OFF_YX2 + b * 256 + c] + 1.f;
            xw[(size_t)(b * 256 + i) * 256 + c] = fmaf(yx2, weighted, yx1);
        }
    }
}

extern "C" void kernel_launch(void* const* d_in, const int* in_sizes, int n_in,
                              void* d_out, int out_size, void* d_ws, size_t ws_size,
                              hipStream_t stream) {
    const float* x        = (const float*)d_in[0];
    const float* e        = (const float*)d_in[1];
    const float* y        = (const float*)d_in[2];
    const float* nm       = (const float*)d_in[3];
    const float* Wq       = (const float*)d_in[4];
    const float* Wk       = (const float*)d_in[5];
    const float* Wv       = (const float*)d_in[6];
    const float* We_mul   = (const float*)d_in[7];
    const float* We_add   = (const float*)d_in[8];
    const float* Wye_add  = (const float*)d_in[9];
    const float* Wye_mul  = (const float*)d_in[10];
    const float* Wyx_add  = (const float*)d_in[11];
    const float* Wyx_mul  = (const float*)d_in[12];
    const float* Wyy      = (const float*)d_in[13];
    const float* Wxy      = (const float*)d_in[14];
    const float* bxy      = (const float*)d_in[15];
    const float* Wey      = (const float*)d_in[16];
    const float* bey      = (const float*)d_in[17];
    const float* We_out   = (const float*)d_in[18];
    const float* be_out   = (const float*)d_in[19];
    const float* Wx_out   = (const float*)d_in[20];
    const float* bx_out   = (const float*)d_in[21];
    const float* Wy_out   = (const float*)d_in[22];
    const float* by_out   = (const float*)d_in[23];

    float* ws   = (float*)d_ws;
    float* outX = (float*)d_out;                       // 262144
    float* outE = (float*)d_out + 262144;              // 16777216
    float* outY = (float*)d_out + 262144 + 16777216;   // 256

    qkv_kernel<<<dim3(64, 3), 256, 0, stream>>>(x, Wq, Wk, Wv, nm, ws);
    yproj_kernel<<<4, 256, 0, stream>>>(y, Wye_add, Wye_mul, Wyx_add, Wyx_mul, ws);
    epoolA_kernel<<<dim3(64, 4), 256, 0, stream>>>(e, ws);
    poolB_kernel<<<4, 256, 0, stream>>>(x, ws);
    newy_kernel<<<1, 256, 0, stream>>>(y, Wyy, Wxy, bxy, Wey, bey, Wy_out, by_out, ws, outY);
    fusedmfma_kernel<<<dim3(256, 4), 256, 0, stream>>>(e, nm, We_mul, We_add, We_out, be_out,
                                                       ws, outE, ws + OFF_XW);
    rowgemm_kernel<<<64, 256, 0, stream>>>(ws + OFF_XW, Wx_out, bx_out, nm, outX);
}